// Round 2
// baseline (260.711 us; speedup 1.0000x reference)
//
#include <hip/hip_runtime.h>

// PerceptronSP: 8000 independent per-pixel MLPs sharing input x.
//   h1 = leaky(x @ W1[p] + b1[p])   [32x25]@[25x128]
//   h2 = leaky(h1 @ W2[p] + b2[p])  [32x128]@[128x128]
//   y[:,p] = h2 @ W3[p] + b3[p]
// Memory-bound: ~640 MB of weights streamed once -> ~102 us floor @ 6.3 TB/s.

constexpr int DIM_IN = 25;
constexpr int H      = 128;
constexpr int P      = 8000;
constexpr int BS     = 32;
constexpr float NEG  = 0.01f;

__device__ __forceinline__ float leaky(float v) { return v >= 0.f ? v : NEG * v; }

__global__ __launch_bounds__(256, 4) void pixel_mlp_kernel(
    const float* __restrict__ x,    // [BS][DIM_IN]
    const float* __restrict__ W1,   // [P][DIM_IN][H]
    const float* __restrict__ b1,   // [P][H]
    const float* __restrict__ W2,   // [P][H][H]
    const float* __restrict__ b2,   // [P][H]
    const float* __restrict__ W3,   // [P][H]
    const float* __restrict__ b3,   // [P]
    float* __restrict__ y)          // [BS][P]
{
    const int p  = blockIdx.x;
    const int t  = threadIdx.x;
    const int kg = t & 31;          // 32 k-groups of 4 columns
    const int bg = t >> 5;          // 8 b-groups of 4 rows
    const int k0 = kg << 2;
    const int b0 = bg << 2;

    __shared__ float sxT[DIM_IN][BS];   // x transposed: [d][b]
    __shared__ float h1s[BS][H];        // layer-1 activations

    // stage x^T into LDS (800 elements, 256 threads -> strided loop!)
    for (int i = t; i < DIM_IN * BS; i += 256) {
        const int d = i >> 5, b = i & 31;
        sxT[d][b] = x[b * DIM_IN + d];
    }
    __syncthreads();

    const float* W1p = W1 + (size_t)p * (DIM_IN * H);
    const float* W2p = W2 + (size_t)p * (H * H);

    // ---------------- layer 1: h1 = leaky(x @ W1 + b1) ----------------
    {
        float acc[4][4];
        const float4 bb = *reinterpret_cast<const float4*>(b1 + (size_t)p * H + k0);
        const float bv[4] = {bb.x, bb.y, bb.z, bb.w};
        #pragma unroll
        for (int i = 0; i < 4; ++i)
            #pragma unroll
            for (int j = 0; j < 4; ++j)
                acc[i][j] = bv[j];

        #pragma unroll 5
        for (int d = 0; d < DIM_IN; ++d) {
            const float4 a4 = *reinterpret_cast<const float4*>(&sxT[d][b0]);
            const float4 w4 = *reinterpret_cast<const float4*>(W1p + d * H + k0);
            const float av[4] = {a4.x, a4.y, a4.z, a4.w};
            const float wv[4] = {w4.x, w4.y, w4.z, w4.w};
            #pragma unroll
            for (int i = 0; i < 4; ++i)
                #pragma unroll
                for (int j = 0; j < 4; ++j)
                    acc[i][j] += av[i] * wv[j];
        }

        #pragma unroll
        for (int i = 0; i < 4; ++i) {
            float4 o;
            o.x = leaky(acc[i][0]); o.y = leaky(acc[i][1]);
            o.z = leaky(acc[i][2]); o.w = leaky(acc[i][3]);
            *reinterpret_cast<float4*>(&h1s[b0 + i][k0]) = o;  // conflict-free: lanes hit consecutive 16B
        }
    }
    __syncthreads();

    // ---------------- layer 2: h2 = leaky(h1 @ W2 + b2) ----------------
    float acc2[4][4];
    {
        const float4 bb = *reinterpret_cast<const float4*>(b2 + (size_t)p * H + k0);
        const float bv[4] = {bb.x, bb.y, bb.z, bb.w};
        #pragma unroll
        for (int i = 0; i < 4; ++i)
            #pragma unroll
            for (int j = 0; j < 4; ++j)
                acc2[i][j] = bv[j];

        #pragma unroll 8
        for (int h0 = 0; h0 < H; h0 += 4) {
            float a[4][4];
            #pragma unroll
            for (int i = 0; i < 4; ++i) {
                // half-wave-uniform address -> LDS broadcast, no bank conflicts
                const float4 a4 = *reinterpret_cast<const float4*>(&h1s[b0 + i][h0]);
                a[i][0] = a4.x; a[i][1] = a4.y; a[i][2] = a4.z; a[i][3] = a4.w;
            }
            #pragma unroll
            for (int hh = 0; hh < 4; ++hh) {
                // lanes 0..31 cover 512B of a W2 row -> fully coalesced stream
                const float4 w4 = *reinterpret_cast<const float4*>(W2p + (h0 + hh) * H + k0);
                const float wv[4] = {w4.x, w4.y, w4.z, w4.w};
                #pragma unroll
                for (int i = 0; i < 4; ++i)
                    #pragma unroll
                    for (int j = 0; j < 4; ++j)
                        acc2[i][j] += a[i][hh] * wv[j];
            }
        }
    }

    // ---------------- layer 3: y = h2 @ W3 + b3 ----------------
    const float4 w34 = *reinterpret_cast<const float4*>(W3 + (size_t)p * H + k0);
    const float w3v[4] = {w34.x, w34.y, w34.z, w34.w};
    float part[4];
    #pragma unroll
    for (int i = 0; i < 4; ++i) {
        float s = 0.f;
        #pragma unroll
        for (int j = 0; j < 4; ++j)
            s += leaky(acc2[i][j]) * w3v[j];
        part[i] = s;
    }
    // butterfly-reduce across the 32 k-group lanes (width 32 = kg dimension)
    #pragma unroll
    for (int m = 16; m >= 1; m >>= 1) {
        #pragma unroll
        for (int i = 0; i < 4; ++i)
            part[i] += __shfl_xor(part[i], m, 32);
    }
    if (kg == 0) {
        const float bias = b3[p];
        #pragma unroll
        for (int i = 0; i < 4; ++i)
            y[(size_t)(b0 + i) * P + p] = part[i] + bias;
    }
}

extern "C" void kernel_launch(void* const* d_in, const int* in_sizes, int n_in,
                              void* d_out, int out_size, void* d_ws, size_t ws_size,
                              hipStream_t stream) {
    const float* x  = (const float*)d_in[0];
    const float* W1 = (const float*)d_in[1];
    const float* b1 = (const float*)d_in[2];
    const float* W2 = (const float*)d_in[3];
    const float* b2 = (const float*)d_in[4];
    const float* W3 = (const float*)d_in[5];
    const float* b3 = (const float*)d_in[6];
    float* y = (float*)d_out;

    pixel_mlp_kernel<<<dim3(P), dim3(256), 0, stream>>>(x, W1, b1, W2, b2, W3, b3, y);
}

// Round 3
// 194.543 us; speedup vs baseline: 1.3401x; 1.3401x over previous
//
#include <hip/hip_runtime.h>

// PerceptronSP: 8000 independent per-pixel MLPs sharing input x.
//   h1 = leaky(x @ W1[p] + b1[p])   [32x25]@[25x128]
//   h2 = leaky(h1 @ W2[p] + b2[p])  [32x128]@[128x128]
//   y[:,p] = h2 @ W3[p] + b3[p]
// Memory-bound: ~640 MB of weights streamed once -> ~100 us floor @ 6.6 TB/s.
//
// Mapping: ONE WAVE PER PIXEL. lane = bg*16+kg (bg=lane>>4, kg=lane&15).
//   lane owns rows 8*bg..8*bg+7  x  cols {4kg..4kg+3} u {64+4kg..64+4kg+3}.
// -> each W1/W2 row is fetched by exactly 2 fully-dense 256B wave instructions
//    (1x L1/HBM request traffic), 8 FMAs per loaded W2 element.

constexpr int DIM_IN = 25;
constexpr int H      = 128;
constexpr int P      = 8000;
constexpr int BS     = 32;
constexpr float NEG  = 0.01f;

__device__ __forceinline__ float leaky(float v) { return v >= 0.f ? v : NEG * v; }

__global__ __launch_bounds__(64, 2) void pixel_mlp_kernel(
    const float* __restrict__ x,    // [BS][DIM_IN]
    const float* __restrict__ W1,   // [P][DIM_IN][H]
    const float* __restrict__ b1,   // [P][H]
    const float* __restrict__ W2,   // [P][H][H]
    const float* __restrict__ b2,   // [P][H]
    const float* __restrict__ W3,   // [P][H]
    const float* __restrict__ b3,   // [P]
    float* __restrict__ y)          // [BS][P]
{
    const int p  = blockIdx.x;
    const int t  = threadIdx.x;     // 0..63, one wave
    const int kg = t & 15;          // col group: cols 4kg.. and 64+4kg..
    const int bg = t >> 4;          // row group: rows 8bg..8bg+7
    const int c0 = kg << 2;         // first col of low half
    const int r0 = bg << 3;         // first row

    __shared__ float sxT[DIM_IN][BS];   // x transposed: [d][b]
    __shared__ float h1s[BS][H];        // layer-1 activations (per-wave private)

    // stage x^T (800 elems, 64 threads)
    for (int i = t; i < DIM_IN * BS; i += 64) {
        const int d = i >> 5, b = i & 31;
        sxT[d][b] = x[b * DIM_IN + d];
    }
    __syncthreads();   // single-wave block: cheap

    const float* W1p = W1 + (size_t)p * (DIM_IN * H);
    const float* W2p = W2 + (size_t)p * (H * H);

    // ---------------- layer 1: h1 = leaky(x @ W1 + b1) ----------------
    {
        float acc1[8][8];
        {
            const float4 bl = *reinterpret_cast<const float4*>(b1 + (size_t)p * H + c0);
            const float4 bh = *reinterpret_cast<const float4*>(b1 + (size_t)p * H + 64 + c0);
            const float bv[8] = {bl.x, bl.y, bl.z, bl.w, bh.x, bh.y, bh.z, bh.w};
            #pragma unroll
            for (int i = 0; i < 8; ++i)
                #pragma unroll
                for (int c = 0; c < 8; ++c)
                    acc1[i][c] = bv[c];
        }

        for (int d = 0; d < DIM_IN; ++d) {
            // x rows: 2 b128 broadcasts
            const float4 a0 = *reinterpret_cast<const float4*>(&sxT[d][r0]);
            const float4 a1 = *reinterpret_cast<const float4*>(&sxT[d][r0 + 4]);
            const float av[8] = {a0.x, a0.y, a0.z, a0.w, a1.x, a1.y, a1.z, a1.w};
            // W1 row: 2 dense 256B loads per wave
            const float4 wl = *reinterpret_cast<const float4*>(W1p + d * H + c0);
            const float4 wh = *reinterpret_cast<const float4*>(W1p + d * H + 64 + c0);
            const float wv[8] = {wl.x, wl.y, wl.z, wl.w, wh.x, wh.y, wh.z, wh.w};
            #pragma unroll
            for (int i = 0; i < 8; ++i)
                #pragma unroll
                for (int c = 0; c < 8; ++c)
                    acc1[i][c] += av[i] * wv[c];
        }

        // write h1 (leaky) — each instr: 16 lanes x 16B contiguous 256B, conflict-free
        #pragma unroll
        for (int i = 0; i < 8; ++i) {
            float4 ol, oh;
            ol.x = leaky(acc1[i][0]); ol.y = leaky(acc1[i][1]);
            ol.z = leaky(acc1[i][2]); ol.w = leaky(acc1[i][3]);
            oh.x = leaky(acc1[i][4]); oh.y = leaky(acc1[i][5]);
            oh.z = leaky(acc1[i][6]); oh.w = leaky(acc1[i][7]);
            *reinterpret_cast<float4*>(&h1s[r0 + i][c0])      = ol;
            *reinterpret_cast<float4*>(&h1s[r0 + i][64 + c0]) = oh;
        }
    }
    __syncthreads();   // wave-internal ordering (lgkmcnt); barrier is cheap here

    // ---------------- layer 2: h2 = leaky(h1 @ W2 + b2) ----------------
    float acc2[8][8];
    {
        const float4 bl = *reinterpret_cast<const float4*>(b2 + (size_t)p * H + c0);
        const float4 bh = *reinterpret_cast<const float4*>(b2 + (size_t)p * H + 64 + c0);
        const float bv[8] = {bl.x, bl.y, bl.z, bl.w, bh.x, bh.y, bh.z, bh.w};
        #pragma unroll
        for (int i = 0; i < 8; ++i)
            #pragma unroll
            for (int c = 0; c < 8; ++c)
                acc2[i][c] = bv[c];
    }

    #pragma unroll 2
    for (int h0 = 0; h0 < H; h0 += 4) {
        // W2 rows h0..h0+3: 8 dense 256B wave loads (the main HBM stream)
        float wv[4][8];
        #pragma unroll
        for (int r = 0; r < 4; ++r) {
            const float4 wl = *reinterpret_cast<const float4*>(W2p + (h0 + r) * H + c0);
            const float4 wh = *reinterpret_cast<const float4*>(W2p + (h0 + r) * H + 64 + c0);
            wv[r][0] = wl.x; wv[r][1] = wl.y; wv[r][2] = wl.z; wv[r][3] = wl.w;
            wv[r][4] = wh.x; wv[r][5] = wh.y; wv[r][6] = wh.z; wv[r][7] = wh.w;
        }
        // h1 rows r0..r0+7, cols h0..h0+3: 8 b128 broadcast reads (4 addrs/wave)
        float av[8][4];
        #pragma unroll
        for (int i = 0; i < 8; ++i) {
            const float4 a4 = *reinterpret_cast<const float4*>(&h1s[r0 + i][h0]);
            av[i][0] = a4.x; av[i][1] = a4.y; av[i][2] = a4.z; av[i][3] = a4.w;
        }
        // 256 FMAs per quad: 8 FMAs per loaded W2 element
        #pragma unroll
        for (int r = 0; r < 4; ++r)
            #pragma unroll
            for (int i = 0; i < 8; ++i)
                #pragma unroll
                for (int c = 0; c < 8; ++c)
                    acc2[i][c] += av[i][r] * wv[r][c];
    }

    // ---------------- layer 3: y = leaky(h2) @ W3 + b3 ----------------
    const float4 w3l = *reinterpret_cast<const float4*>(W3 + (size_t)p * H + c0);
    const float4 w3h = *reinterpret_cast<const float4*>(W3 + (size_t)p * H + 64 + c0);
    const float w3v[8] = {w3l.x, w3l.y, w3l.z, w3l.w, w3h.x, w3h.y, w3h.z, w3h.w};

    float part[8];
    #pragma unroll
    for (int i = 0; i < 8; ++i) {
        float s = 0.f;
        #pragma unroll
        for (int c = 0; c < 8; ++c)
            s += leaky(acc2[i][c]) * w3v[c];
        part[i] = s;
    }
    // reduce across the 16 kg lanes (xor masks 1,2,4,8 stay within the 16-group)
    #pragma unroll
    for (int m = 8; m >= 1; m >>= 1) {
        #pragma unroll
        for (int i = 0; i < 8; ++i)
            part[i] += __shfl_xor(part[i], m);
    }
    if (kg == 0) {
        const float bias = b3[p];
        #pragma unroll
        for (int i = 0; i < 8; ++i)
            y[(size_t)(r0 + i) * P + p] = part[i] + bias;
    }
}

extern "C" void kernel_launch(void* const* d_in, const int* in_sizes, int n_in,
                              void* d_out, int out_size, void* d_ws, size_t ws_size,
                              hipStream_t stream) {
    const float* x  = (const float*)d_in[0];
    const float* W1 = (const float*)d_in[1];
    const float* b1 = (const float*)d_in[2];
    const float* W2 = (const float*)d_in[3];
    const float* b2 = (const float*)d_in[4];
    const float* W3 = (const float*)d_in[5];
    const float* b3 = (const float*)d_in[6];
    float* y = (float*)d_out;

    pixel_mlp_kernel<<<dim3(P), dim3(64), 0, stream>>>(x, W1, b1, W2, b2, W3, b3, y);
}